// Round 1
// baseline (779.900 us; speedup 1.0000x reference)
//
#include <hip/hip_runtime.h>
#include <stdint.h>

// ---------------------------------------------------------------------------
// RULSTM collapsed: y = h2 @ Wc.T + bc where h2 = 2 unroll-LSTM steps from
// rolling-LSTM final state. All big matmuls via bf16 MFMA (16x16x32), fp32
// accum; LSTM cell state fp32; weights pre-summed ([x,x] concat trick).
// ---------------------------------------------------------------------------

typedef __attribute__((ext_vector_type(8))) short short8;
typedef __attribute__((ext_vector_type(4))) float f32x4;

#define SEQ   16
#define BATCH 512
#define HID   1024
#define GATE4 4096
#define FEAT  2048
#define ACTN  2513
#define ACTP  2560
#define SB    (SEQ * BATCH)   // 8192

// bf16 conversions (manual, RNE) so we don't depend on hip_bf16 API details.
__device__ __forceinline__ unsigned short f2bf(float x) {
    unsigned u = __float_as_uint(x);
    u = u + 0x7FFFu + ((u >> 16) & 1u);
    return (unsigned short)(u >> 16);
}
__device__ __forceinline__ float bf2f(unsigned short h) {
    return __uint_as_float(((unsigned)h) << 16);
}

__device__ __forceinline__ void gload_lds16(const void* g, void* l) {
    __builtin_amdgcn_global_load_lds(
        (const __attribute__((address_space(1))) void*)g,
        (__attribute__((address_space(3))) void*)l,
        16, 0, 0);
}

// ---------------------------------------------------------------------------
// C[M,N] = A[M,K](bf16) @ W[N,K](bf16)^T  (+ bias[N]) (+ add[M,N] bf16)
// 128x128 tile, BK=64, 4 waves, each wave 64x64 (4x4 frags of 16x16x32).
// ---------------------------------------------------------------------------
template<bool OUT_BF16, bool HAS_BIAS, bool HAS_ADD, bool GUARD>
__global__ __launch_bounds__(256)
void gemm_bt(const unsigned short* __restrict__ A,
             const unsigned short* __restrict__ W,
             void* __restrict__ Cv,
             const float* __restrict__ bias,
             const unsigned short* __restrict__ add,
             int M, int N, int K, int ldc, int nvalid)
{
    __shared__ __align__(16) unsigned short sA[128 * 64];
    __shared__ __align__(16) unsigned short sB[128 * 64];

    const int t    = threadIdx.x;
    const int lane = t & 63;
    const int wave = t >> 6;
    const int m0   = blockIdx.y * 128;
    const int n0   = blockIdx.x * 128;
    const int srow = t >> 3;          // 0..31
    const int scol = (t & 7) * 8;     // bf16 col within 64
    const int wm   = (wave >> 1) * 64;
    const int wn   = (wave & 1) * 64;
    const int fl   = lane & 15;
    const int fk   = (lane >> 4) * 8;

    f32x4 acc[4][4] = {};

    const unsigned short* Abase = A + (size_t)(m0 + srow) * K + scol;
    const unsigned short* Wbase = W + (size_t)(n0 + srow) * K + scol;
    unsigned short* sAd = &sA[srow * 64 + scol];
    unsigned short* sBd = &sB[srow * 64 + scol];

    for (int kt = 0; kt < K; kt += 64) {
#pragma unroll
        for (int j = 0; j < 4; ++j) {
            gload_lds16(Abase + (size_t)j * 32 * K + kt, sAd + j * 32 * 64);
            gload_lds16(Wbase + (size_t)j * 32 * K + kt, sBd + j * 32 * 64);
        }
        __syncthreads();
#pragma unroll
        for (int kk = 0; kk < 64; kk += 32) {
            short8 af[4], bfrag[4];
#pragma unroll
            for (int i = 0; i < 4; ++i)
                af[i] = *(const short8*)&sA[(wm + i * 16 + fl) * 64 + kk + fk];
#pragma unroll
            for (int i = 0; i < 4; ++i)
                bfrag[i] = *(const short8*)&sB[(wn + i * 16 + fl) * 64 + kk + fk];
#pragma unroll
            for (int mi = 0; mi < 4; ++mi)
#pragma unroll
                for (int ni = 0; ni < 4; ++ni)
                    acc[mi][ni] = __builtin_amdgcn_mfma_f32_16x16x32_bf16(
                        af[mi], bfrag[ni], acc[mi][ni], 0, 0, 0);
        }
        __syncthreads();
    }

    // epilogue: C/D layout col=lane&15, row=(lane>>4)*4+reg  [m89-verified]
    const int crb = (lane >> 4) * 4;
#pragma unroll
    for (int mi = 0; mi < 4; ++mi) {
#pragma unroll
        for (int ni = 0; ni < 4; ++ni) {
            const int col = n0 + wn + ni * 16 + fl;
            if (GUARD && col >= nvalid) continue;
            const float bv = HAS_BIAS ? bias[col] : 0.0f;
#pragma unroll
            for (int r = 0; r < 4; ++r) {
                const int row = m0 + wm + mi * 16 + crb + r;
                float v = acc[mi][ni][r] + bv;
                if (HAS_ADD) v += bf2f(add[(size_t)row * N + col]);
                if (OUT_BF16)
                    ((unsigned short*)Cv)[(size_t)row * ldc + col] = f2bf(v);
                else
                    ((float*)Cv)[(size_t)row * ldc + col] = v;
            }
        }
    }
}

// ---------------------------------------------------------------------------
// Elementwise kernels
// ---------------------------------------------------------------------------
__global__ void lstm_cell_k(const float* __restrict__ gates,  // [512,4096] i,f,g,o
                            float* __restrict__ c,            // [512,1024] in/out
                            unsigned short* __restrict__ h)   // [512,1024] bf16 out
{
    int idx = blockIdx.x * blockDim.x + threadIdx.x;  // < 512*1024
    int b = idx >> 10, j = idx & 1023;
    const float* g = gates + ((size_t)b << 12);
    float gi = g[j], gf = g[j + 1024], gg = g[j + 2048], go = g[j + 3072];
    float si = 1.f / (1.f + __expf(-gi));
    float sf = 1.f / (1.f + __expf(-gf));
    float so = 1.f / (1.f + __expf(-go));
    float cv = sf * c[idx] + si * tanhf(gg);
    c[idx] = cv;
    h[idx] = f2bf(so * tanhf(cv));
}

__global__ void cvt_bf16_k(const float4* __restrict__ in,
                           ushort4* __restrict__ out, int n4)
{
    int i = blockIdx.x * blockDim.x + threadIdx.x;
    if (i >= n4) return;
    float4 v = in[i];
    ushort4 o;
    o.x = f2bf(v.x); o.y = f2bf(v.y); o.z = f2bf(v.z); o.w = f2bf(v.w);
    out[i] = o;
}

// out[g][k] = bf16(W[g][k] + W[g][1024+k]), W is [4096,2048]
__global__ void sum_halves_k(const float* __restrict__ W,
                             unsigned short* __restrict__ out)
{
    int i = blockIdx.x * blockDim.x + threadIdx.x;  // < 4096*256
    int g = i >> 8, k4 = (i & 255) * 4;
    const float* row = W + (size_t)g * 2048;
    float4 a = *(const float4*)(row + k4);
    float4 b = *(const float4*)(row + 1024 + k4);
    ushort4 o;
    o.x = f2bf(a.x + b.x); o.y = f2bf(a.y + b.y);
    o.z = f2bf(a.z + b.z); o.w = f2bf(a.w + b.w);
    *(ushort4*)(out + (size_t)g * 1024 + k4) = o;
}

// Wc [2513,1024] -> bf16 padded [2560,1024] (zero rows beyond 2513)
__global__ void pad_wc_k(const float* __restrict__ Wc,
                         unsigned short* __restrict__ out)
{
    int i = blockIdx.x * blockDim.x + threadIdx.x;  // < 2560*256
    int g = i >> 8, k4 = (i & 255) * 4;
    ushort4 o;
    if (g < ACTN) {
        float4 v = *(const float4*)(Wc + (size_t)g * 1024 + k4);
        o.x = f2bf(v.x); o.y = f2bf(v.y); o.z = f2bf(v.z); o.w = f2bf(v.w);
    } else {
        o.x = o.y = o.z = o.w = 0;
    }
    *(ushort4*)(out + (size_t)g * 1024 + k4) = o;
}

__global__ void pad_bc_k(const float* __restrict__ bc, float* __restrict__ out)
{
    int i = blockIdx.x * blockDim.x + threadIdx.x;
    if (i < ACTP) out[i] = (i < ACTN) ? bc[i] : 0.f;
}

__global__ void sum_bias_k(const float* __restrict__ a,
                           const float* __restrict__ b,
                           float* __restrict__ out, int n)
{
    int i = blockIdx.x * blockDim.x + threadIdx.x;
    if (i < n) out[i] = a[i] + b[i];
}

__global__ void zero_hc_k(unsigned short* __restrict__ h, float* __restrict__ c)
{
    int i = blockIdx.x * blockDim.x + threadIdx.x;  // < 512*1024
    h[i] = 0;
    c[i] = 0.f;
}

// ---------------------------------------------------------------------------
// Workspace layout (bytes)
// ---------------------------------------------------------------------------
#define OFF_IN_BF 0ull                              // 8192*2048*2
#define OFF_X_BF  (OFF_IN_BF + 33554432ull)         // 8192*1024*2
#define OFF_XGR   (OFF_X_BF + 16777216ull)          // 8192*4096*2
#define OFF_W1    (OFF_XGR + 67108864ull)           // 1024*2048*2
#define OFF_WR    (OFF_W1 + 4194304ull)             // 4096*1024*2
#define OFF_WHHR  (OFF_WR + 8388608ull)
#define OFF_WU    (OFF_WHHR + 8388608ull)
#define OFF_WHHU  (OFF_WU + 8388608ull)
#define OFF_WC    (OFF_WHHU + 8388608ull)           // 2560*1024*2
#define OFF_XGU   (OFF_WC + 5242880ull)             // 512*4096*2
#define OFF_GATES (OFF_XGU + 4194304ull)            // 512*4096*4
#define OFF_H     (OFF_GATES + 8388608ull)          // 512*1024*2
#define OFF_C     (OFF_H + 1048576ull)              // 512*1024*4
#define OFF_BC    (OFF_C + 2097152ull)              // 2560*4
#define OFF_BU    (OFF_BC + 10240ull)               // 4096*4

extern "C" void kernel_launch(void* const* d_in, const int* in_sizes, int n_in,
                              void* d_out, int out_size, void* d_ws, size_t ws_size,
                              hipStream_t stream)
{
    const float* inputs = (const float*)d_in[0];
    const float* W1     = (const float*)d_in[1];
    const float* b1     = (const float*)d_in[2];
    const float* Wih_r  = (const float*)d_in[3];
    const float* Whh_r  = (const float*)d_in[4];
    const float* bih_r  = (const float*)d_in[5];
    const float* bhh_r  = (const float*)d_in[6];
    const float* Wih_u  = (const float*)d_in[7];
    const float* Whh_u  = (const float*)d_in[8];
    const float* bih_u  = (const float*)d_in[9];
    const float* bhh_u  = (const float*)d_in[10];
    const float* Wc     = (const float*)d_in[11];
    const float* bc     = (const float*)d_in[12];
    float* out = (float*)d_out;
    char* ws = (char*)d_ws;

    unsigned short* in_bf = (unsigned short*)(ws + OFF_IN_BF);
    unsigned short* x_bf  = (unsigned short*)(ws + OFF_X_BF);
    unsigned short* xg_r  = (unsigned short*)(ws + OFF_XGR);
    unsigned short* W1b   = (unsigned short*)(ws + OFF_W1);
    unsigned short* Wrb   = (unsigned short*)(ws + OFF_WR);
    unsigned short* Whhrb = (unsigned short*)(ws + OFF_WHHR);
    unsigned short* Wub   = (unsigned short*)(ws + OFF_WU);
    unsigned short* Whhub = (unsigned short*)(ws + OFF_WHHU);
    unsigned short* Wcb   = (unsigned short*)(ws + OFF_WC);
    unsigned short* xg_u  = (unsigned short*)(ws + OFF_XGU);
    float*          gates = (float*)(ws + OFF_GATES);
    unsigned short* h_bf  = (unsigned short*)(ws + OFF_H);
    float*          c_buf = (float*)(ws + OFF_C);
    float*          bc_p  = (float*)(ws + OFF_BC);
    float*          bu_s  = (float*)(ws + OFF_BU);

    const dim3 blk(256);

    // ---- prep: conversions / folds ----
    cvt_bf16_k<<<dim3(SB * FEAT / 4 / 256), blk, 0, stream>>>(
        (const float4*)inputs, (ushort4*)in_bf, SB * FEAT / 4);
    cvt_bf16_k<<<dim3(HID * FEAT / 4 / 256), blk, 0, stream>>>(
        (const float4*)W1, (ushort4*)W1b, HID * FEAT / 4);
    sum_halves_k<<<dim3(GATE4 * 256 / 256), blk, 0, stream>>>(Wih_r, Wrb);
    sum_halves_k<<<dim3(GATE4 * 256 / 256), blk, 0, stream>>>(Wih_u, Wub);
    cvt_bf16_k<<<dim3(GATE4 * HID / 4 / 256), blk, 0, stream>>>(
        (const float4*)Whh_r, (ushort4*)Whhrb, GATE4 * HID / 4);
    cvt_bf16_k<<<dim3(GATE4 * HID / 4 / 256), blk, 0, stream>>>(
        (const float4*)Whh_u, (ushort4*)Whhub, GATE4 * HID / 4);
    pad_wc_k<<<dim3(ACTP * 256 / 256), blk, 0, stream>>>(Wc, Wcb);
    pad_bc_k<<<dim3((ACTP + 255) / 256), blk, 0, stream>>>(bc, bc_p);
    sum_bias_k<<<dim3(GATE4 / 256), blk, 0, stream>>>(bih_u, bhh_u, bu_s, GATE4);
    zero_hc_k<<<dim3(BATCH * HID / 256), blk, 0, stream>>>(h_bf, c_buf);

    // ---- G1: x = inputs @ W1^T + b1  -> bf16 [8192,1024] ----
    gemm_bt<true, true, false, false><<<dim3(HID / 128, SB / 128), blk, 0, stream>>>(
        in_bf, W1b, x_bf, b1, nullptr, SB, HID, FEAT, HID, HID);

    // ---- G2: xg_r = x @ Wr_eff^T + bih_r -> bf16 [8192,4096] ----
    gemm_bt<true, true, false, false><<<dim3(GATE4 / 128, SB / 128), blk, 0, stream>>>(
        x_bf, Wrb, xg_r, bih_r, nullptr, SB, GATE4, HID, GATE4, GATE4);

    // ---- rolling LSTM: 16 sequential steps ----
    for (int s = 0; s < SEQ; ++s) {
        gemm_bt<false, true, true, false><<<dim3(GATE4 / 128, BATCH / 128), blk, 0, stream>>>(
            h_bf, Whhrb, gates, bhh_r, xg_r + (size_t)s * BATCH * GATE4,
            BATCH, GATE4, HID, GATE4, GATE4);
        lstm_cell_k<<<dim3(BATCH * HID / 256), blk, 0, stream>>>(gates, c_buf, h_bf);
    }

    // ---- xg_u[15] = x[15] @ Wu_eff^T + (bih_u + bhh_u) -> bf16 [512,4096] ----
    gemm_bt<true, true, false, false><<<dim3(GATE4 / 128, BATCH / 128), blk, 0, stream>>>(
        x_bf + (size_t)(SEQ - 1) * BATCH * HID, Wub, xg_u, bu_s, nullptr,
        BATCH, GATE4, HID, GATE4, GATE4);

    // ---- 2 unroll steps ----
    for (int s = 0; s < 2; ++s) {
        gemm_bt<false, false, true, false><<<dim3(GATE4 / 128, BATCH / 128), blk, 0, stream>>>(
            h_bf, Whhub, gates, nullptr, xg_u, BATCH, GATE4, HID, GATE4, GATE4);
        lstm_cell_k<<<dim3(BATCH * HID / 256), blk, 0, stream>>>(gates, c_buf, h_bf);
    }

    // ---- classifier: y = h @ Wc^T + bc -> fp32 [512,2513] ----
    gemm_bt<false, true, false, true><<<dim3(ACTP / 128, BATCH / 128), blk, 0, stream>>>(
        h_bf, Wcb, out, bc_p, nullptr, BATCH, ACTP, HID, ACTN, ACTN);
}

// Round 2
// 577.769 us; speedup vs baseline: 1.3498x; 1.3498x over previous
//
#include <hip/hip_runtime.h>
#include <stdint.h>

// ---------------------------------------------------------------------------
// RULSTM collapsed: y = h2 @ Wc.T + bc where h2 = 2 unroll-LSTM steps from
// rolling-LSTM final state. Gate axis PERMUTED (n_new = (j&15)|gate<<4|(j>>4)<<6)
// so each 64-col group = 16 j x 4 gates -> LSTM cell fused into GEMM epilogue.
// ---------------------------------------------------------------------------

typedef __attribute__((ext_vector_type(8))) short short8;
typedef __attribute__((ext_vector_type(4))) float f32x4;

#define SEQ   16
#define BATCH 512
#define HID   1024
#define GATE4 4096
#define FEAT  2048
#define ACTN  2513
#define ACTP  2560
#define SB    (SEQ * BATCH)   // 8192

__device__ __forceinline__ unsigned short f2bf(float x) {
    unsigned u = __float_as_uint(x);
    u = u + 0x7FFFu + ((u >> 16) & 1u);
    return (unsigned short)(u >> 16);
}
__device__ __forceinline__ float bf2f(unsigned short h) {
    return __uint_as_float(((unsigned)h) << 16);
}
__device__ __forceinline__ float sigm(float x) { return 1.f / (1.f + __expf(-x)); }

__device__ __forceinline__ int gate_unperm(int nn) {
    // inverse of n_new = (j&15) | gate<<4 | (j>>4)<<6 ; n_orig = gate*1024 + j
    return (((nn >> 4) & 3) << 10) | ((nn >> 6) << 4) | (nn & 15);
}

__device__ __forceinline__ void gload_lds16(const void* g, void* l) {
    __builtin_amdgcn_global_load_lds(
        (const __attribute__((address_space(1))) void*)g,
        (__attribute__((address_space(3))) void*)l,
        16, 0, 0);
}

// ---------------------------------------------------------------------------
// Generic C[M,N] = A[M,K]@W[N,K]^T (+bias) (+add), 128x128 tile (big GEMMs)
// ---------------------------------------------------------------------------
template<bool OUT_BF16, bool HAS_BIAS, bool GUARD>
__global__ __launch_bounds__(256)
void gemm_bt(const unsigned short* __restrict__ A,
             const unsigned short* __restrict__ W,
             void* __restrict__ Cv,
             const float* __restrict__ bias,
             int M, int N, int K, int ldc, int nvalid)
{
    __shared__ __align__(16) unsigned short sA[128 * 64];
    __shared__ __align__(16) unsigned short sB[128 * 64];

    const int t    = threadIdx.x;
    const int lane = t & 63;
    const int wave = t >> 6;
    const int m0   = blockIdx.y * 128;
    const int n0   = blockIdx.x * 128;
    const int srow = t >> 3;
    const int scol = (t & 7) * 8;
    const int wm   = (wave >> 1) * 64;
    const int wn   = (wave & 1) * 64;
    const int fl   = lane & 15;
    const int fk   = (lane >> 4) * 8;

    f32x4 acc[4][4] = {};

    const unsigned short* Abase = A + (size_t)(m0 + srow) * K + scol;
    const unsigned short* Wbase = W + (size_t)(n0 + srow) * K + scol;
    unsigned short* sAd = &sA[srow * 64 + scol];
    unsigned short* sBd = &sB[srow * 64 + scol];

    for (int kt = 0; kt < K; kt += 64) {
#pragma unroll
        for (int j = 0; j < 4; ++j) {
            gload_lds16(Abase + (size_t)j * 32 * K + kt, sAd + j * 32 * 64);
            gload_lds16(Wbase + (size_t)j * 32 * K + kt, sBd + j * 32 * 64);
        }
        __syncthreads();
#pragma unroll
        for (int kk = 0; kk < 64; kk += 32) {
            short8 af[4], bfrag[4];
#pragma unroll
            for (int i = 0; i < 4; ++i)
                af[i] = *(const short8*)&sA[(wm + i * 16 + fl) * 64 + kk + fk];
#pragma unroll
            for (int i = 0; i < 4; ++i)
                bfrag[i] = *(const short8*)&sB[(wn + i * 16 + fl) * 64 + kk + fk];
#pragma unroll
            for (int mi = 0; mi < 4; ++mi)
#pragma unroll
                for (int ni = 0; ni < 4; ++ni)
                    acc[mi][ni] = __builtin_amdgcn_mfma_f32_16x16x32_bf16(
                        af[mi], bfrag[ni], acc[mi][ni], 0, 0, 0);
        }
        __syncthreads();
    }

    const int crb = (lane >> 4) * 4;
#pragma unroll
    for (int mi = 0; mi < 4; ++mi) {
#pragma unroll
        for (int ni = 0; ni < 4; ++ni) {
            const int col = n0 + wn + ni * 16 + fl;
            if (GUARD && col >= nvalid) continue;
            const float bv = HAS_BIAS ? bias[col] : 0.0f;
#pragma unroll
            for (int r = 0; r < 4; ++r) {
                const int row = m0 + wm + mi * 16 + crb + r;
                float v = acc[mi][ni][r] + bv;
                if (OUT_BF16)
                    ((unsigned short*)Cv)[(size_t)row * ldc + col] = f2bf(v);
                else
                    ((float*)Cv)[(size_t)row * ldc + col] = v;
            }
        }
    }
}

// ---------------------------------------------------------------------------
// Fused LSTM step: gates = h@W^T (+bias) + xg ; cell -> writes h(bf16), c(f32)
// 64x64 tile, 4 waves (16 rows each), grid (4096/64, 512/64) = 512 blocks.
// Gate axis of W/xg/bias is permuted so ni = gate, lane&15 = j&15.
// ---------------------------------------------------------------------------
template<bool HAS_BIAS>
__global__ __launch_bounds__(256)
void lstm_step_fused(const unsigned short* __restrict__ A,   // h [512,1024] bf16
                     const unsigned short* __restrict__ W,   // [4096,1024] bf16 perm
                     const unsigned short* __restrict__ xg,  // [512,4096] bf16 perm
                     const float* __restrict__ bias,         // [4096] perm or null
                     float* __restrict__ c,                  // [512,1024] f32 in/out
                     unsigned short* __restrict__ h)         // [512,1024] bf16 out
{
    __shared__ __align__(16) unsigned short sA[64 * 64];
    __shared__ __align__(16) unsigned short sB[64 * 64];

    const int t    = threadIdx.x;
    const int lane = t & 63;
    const int wave = t >> 6;          // 0..3, 16 rows each
    const int m0   = blockIdx.y * 64;
    const int n0   = blockIdx.x * 64;
    const int srow = t >> 3;          // 0..31
    const int scol = (t & 7) * 8;
    const int wm   = wave * 16;
    const int fl   = lane & 15;
    const int fk   = (lane >> 4) * 8;

    f32x4 acc[4] = {};

    const unsigned short* Abase = A + (size_t)(m0 + srow) * HID + scol;
    const unsigned short* Wbase = W + (size_t)(n0 + srow) * HID + scol;
    unsigned short* sAd = &sA[srow * 64 + scol];
    unsigned short* sBd = &sB[srow * 64 + scol];

    for (int kt = 0; kt < HID; kt += 64) {
#pragma unroll
        for (int j = 0; j < 2; ++j) {
            gload_lds16(Abase + (size_t)j * 32 * HID + kt, sAd + j * 32 * 64);
            gload_lds16(Wbase + (size_t)j * 32 * HID + kt, sBd + j * 32 * 64);
        }
        __syncthreads();
#pragma unroll
        for (int kk = 0; kk < 64; kk += 32) {
            short8 af = *(const short8*)&sA[(wm + fl) * 64 + kk + fk];
#pragma unroll
            for (int ni = 0; ni < 4; ++ni) {
                short8 bfr = *(const short8*)&sB[(ni * 16 + fl) * 64 + kk + fk];
                acc[ni] = __builtin_amdgcn_mfma_f32_16x16x32_bf16(af, bfr, acc[ni], 0, 0, 0);
            }
        }
        __syncthreads();
    }

    // fused cell epilogue: ni = gate (0:i 1:f 2:g 3:o), j = (n0>>6)*16 + fl
    const int crb = (lane >> 4) * 4;
    const int j   = (n0 >> 6) * 16 + fl;
    float bv[4] = {0.f, 0.f, 0.f, 0.f};
    if (HAS_BIAS) {
#pragma unroll
        for (int ni = 0; ni < 4; ++ni) bv[ni] = bias[n0 + ni * 16 + fl];
    }
#pragma unroll
    for (int r = 0; r < 4; ++r) {
        const int b = m0 + wm + crb + r;
        float v[4];
#pragma unroll
        for (int ni = 0; ni < 4; ++ni)
            v[ni] = acc[ni][r] + bv[ni] + bf2f(xg[(size_t)b * GATE4 + n0 + ni * 16 + fl]);
        const int ci = b * HID + j;
        float cv = sigm(v[1]) * c[ci] + sigm(v[0]) * tanhf(v[2]);
        c[ci] = cv;
        h[ci] = f2bf(sigm(v[3]) * tanhf(cv));
    }
}

// ---------------------------------------------------------------------------
// Step 0 of rolling LSTM (h=0, c=0): pure cell on xg_r[0] + bhh
// ---------------------------------------------------------------------------
__global__ void lstm_cell0_k(const unsigned short* __restrict__ xg,  // perm
                             const float* __restrict__ bias,         // perm (bhh_r)
                             float* __restrict__ c, unsigned short* __restrict__ h)
{
    int idx = blockIdx.x * blockDim.x + threadIdx.x;  // < 512*1024
    int b = idx >> 10, j = idx & 1023;
    int base = (j & 15) | ((j >> 4) << 6);
    float v[4];
#pragma unroll
    for (int g = 0; g < 4; ++g) {
        int col = base | (g << 4);
        v[g] = bf2f(xg[(size_t)b * GATE4 + col]) + bias[col];
    }
    float cv = sigm(v[0]) * tanhf(v[2]);   // c_prev = 0
    c[idx] = cv;
    h[idx] = f2bf(sigm(v[3]) * tanhf(cv));
}

// ---------------------------------------------------------------------------
// Prep kernels
// ---------------------------------------------------------------------------
__global__ void cvt_bf16_k(const float4* __restrict__ in,
                           ushort4* __restrict__ out, int n4)
{
    int i = blockIdx.x * blockDim.x + threadIdx.x;
    if (i >= n4) return;
    float4 v = in[i];
    ushort4 o;
    o.x = f2bf(v.x); o.y = f2bf(v.y); o.z = f2bf(v.z); o.w = f2bf(v.w);
    out[i] = o;
}

// out[n_new][k] = bf16(W[n_orig][k] + W[n_orig][1024+k]); W [4096,2048]
__global__ void sum_halves_perm_k(const float* __restrict__ W,
                                  unsigned short* __restrict__ out)
{
    int i = blockIdx.x * blockDim.x + threadIdx.x;  // < 4096*256
    int nn = i >> 8, k4 = (i & 255) * 4;
    int no = gate_unperm(nn);
    const float* row = W + (size_t)no * 2048;
    float4 a = *(const float4*)(row + k4);
    float4 b = *(const float4*)(row + 1024 + k4);
    ushort4 o;
    o.x = f2bf(a.x + b.x); o.y = f2bf(a.y + b.y);
    o.z = f2bf(a.z + b.z); o.w = f2bf(a.w + b.w);
    *(ushort4*)(out + (size_t)nn * 1024 + k4) = o;
}

// out[n_new][k] = bf16(Whh[n_orig][k]); Whh [4096,1024]
__global__ void cvt_perm_k(const float* __restrict__ Win,
                           unsigned short* __restrict__ out)
{
    int i = blockIdx.x * blockDim.x + threadIdx.x;  // < 4096*256
    int nn = i >> 8, k4 = (i & 255) * 4;
    int no = gate_unperm(nn);
    float4 v = *(const float4*)(Win + (size_t)no * HID + k4);
    ushort4 o;
    o.x = f2bf(v.x); o.y = f2bf(v.y); o.z = f2bf(v.z); o.w = f2bf(v.w);
    *(ushort4*)(out + (size_t)nn * HID + k4) = o;
}

// Wc [2513,1024] -> bf16 padded [2560,1024]
__global__ void pad_wc_k(const float* __restrict__ Wc,
                         unsigned short* __restrict__ out)
{
    int i = blockIdx.x * blockDim.x + threadIdx.x;  // < 2560*256
    int g = i >> 8, k4 = (i & 255) * 4;
    ushort4 o;
    if (g < ACTN) {
        float4 v = *(const float4*)(Wc + (size_t)g * 1024 + k4);
        o.x = f2bf(v.x); o.y = f2bf(v.y); o.z = f2bf(v.z); o.w = f2bf(v.w);
    } else {
        o.x = o.y = o.z = o.w = 0;
    }
    *(ushort4*)(out + (size_t)g * 1024 + k4) = o;
}

// permuted biases + padded bc, one launch
__global__ void prep_small_k(const float* __restrict__ bih_r, const float* __restrict__ bhh_r,
                             const float* __restrict__ bih_u, const float* __restrict__ bhh_u,
                             const float* __restrict__ bc,
                             float* __restrict__ bihr_p, float* __restrict__ bhhr_p,
                             float* __restrict__ bu_p, float* __restrict__ bc_p)
{
    int i = blockIdx.x * blockDim.x + threadIdx.x;
    if (i < GATE4) {
        int src = gate_unperm(i);
        bihr_p[i] = bih_r[src];
        bhhr_p[i] = bhh_r[src];
        bu_p[i]   = bih_u[src] + bhh_u[src];
    } else if (i < GATE4 + ACTP) {
        int j = i - GATE4;
        bc_p[j] = (j < ACTN) ? bc[j] : 0.f;
    }
}

// ---------------------------------------------------------------------------
// Workspace layout (bytes)
// ---------------------------------------------------------------------------
#define OFF_IN_BF 0ull                              // 8192*2048*2 = 32MiB
#define OFF_X_BF  (OFF_IN_BF + 33554432ull)         // 16MiB
#define OFF_XGR   (OFF_X_BF + 16777216ull)          // 64MiB
#define OFF_W1    (OFF_XGR + 67108864ull)           // 4MiB
#define OFF_WR    (OFF_W1 + 4194304ull)             // 8MiB
#define OFF_WHHR  (OFF_WR + 8388608ull)             // 8MiB
#define OFF_WU    (OFF_WHHR + 8388608ull)           // 8MiB
#define OFF_WHHU  (OFF_WU + 8388608ull)             // 8MiB
#define OFF_WC    (OFF_WHHU + 8388608ull)           // 5MiB
#define OFF_XGU   (OFF_WC + 5242880ull)             // 4MiB
#define OFF_H     (OFF_XGU + 4194304ull)            // 1MiB
#define OFF_C     (OFF_H + 1048576ull)              // 2MiB
#define OFF_BC    (OFF_C + 2097152ull)              // 10240
#define OFF_BU    (OFF_BC + 10240ull)               // 16384
#define OFF_BIHR  (OFF_BU + 16384ull)               // 16384
#define OFF_BHHR  (OFF_BIHR + 16384ull)             // 16384

extern "C" void kernel_launch(void* const* d_in, const int* in_sizes, int n_in,
                              void* d_out, int out_size, void* d_ws, size_t ws_size,
                              hipStream_t stream)
{
    const float* inputs = (const float*)d_in[0];
    const float* W1     = (const float*)d_in[1];
    const float* b1     = (const float*)d_in[2];
    const float* Wih_r  = (const float*)d_in[3];
    const float* Whh_r  = (const float*)d_in[4];
    const float* bih_r  = (const float*)d_in[5];
    const float* bhh_r  = (const float*)d_in[6];
    const float* Wih_u  = (const float*)d_in[7];
    const float* Whh_u  = (const float*)d_in[8];
    const float* bih_u  = (const float*)d_in[9];
    const float* bhh_u  = (const float*)d_in[10];
    const float* Wc     = (const float*)d_in[11];
    const float* bc     = (const float*)d_in[12];
    float* out = (float*)d_out;
    char* ws = (char*)d_ws;

    unsigned short* in_bf = (unsigned short*)(ws + OFF_IN_BF);
    unsigned short* x_bf  = (unsigned short*)(ws + OFF_X_BF);
    unsigned short* xg_r  = (unsigned short*)(ws + OFF_XGR);
    unsigned short* W1b   = (unsigned short*)(ws + OFF_W1);
    unsigned short* Wrb   = (unsigned short*)(ws + OFF_WR);
    unsigned short* Whhrb = (unsigned short*)(ws + OFF_WHHR);
    unsigned short* Wub   = (unsigned short*)(ws + OFF_WU);
    unsigned short* Whhub = (unsigned short*)(ws + OFF_WHHU);
    unsigned short* Wcb   = (unsigned short*)(ws + OFF_WC);
    unsigned short* xg_u  = (unsigned short*)(ws + OFF_XGU);
    unsigned short* h_bf  = (unsigned short*)(ws + OFF_H);
    float*          c_buf = (float*)(ws + OFF_C);
    float*          bc_p  = (float*)(ws + OFF_BC);
    float*          bu_p  = (float*)(ws + OFF_BU);
    float*          bihr_p= (float*)(ws + OFF_BIHR);
    float*          bhhr_p= (float*)(ws + OFF_BHHR);

    const dim3 blk(256);

    // ---- prep ----
    cvt_bf16_k<<<dim3(SB * FEAT / 4 / 256), blk, 0, stream>>>(
        (const float4*)inputs, (ushort4*)in_bf, SB * FEAT / 4);
    cvt_bf16_k<<<dim3(HID * FEAT / 4 / 256), blk, 0, stream>>>(
        (const float4*)W1, (ushort4*)W1b, HID * FEAT / 4);
    sum_halves_perm_k<<<dim3(GATE4), blk, 0, stream>>>(Wih_r, Wrb);
    sum_halves_perm_k<<<dim3(GATE4), blk, 0, stream>>>(Wih_u, Wub);
    cvt_perm_k<<<dim3(GATE4), blk, 0, stream>>>(Whh_r, Whhrb);
    cvt_perm_k<<<dim3(GATE4), blk, 0, stream>>>(Whh_u, Whhub);
    pad_wc_k<<<dim3(ACTP), blk, 0, stream>>>(Wc, Wcb);
    prep_small_k<<<dim3((GATE4 + ACTP + 255) / 256), blk, 0, stream>>>(
        bih_r, bhh_r, bih_u, bhh_u, bc, bihr_p, bhhr_p, bu_p, bc_p);

    // ---- G1: x = inputs @ W1^T + b1 -> bf16 [8192,1024] ----
    gemm_bt<true, true, false><<<dim3(HID / 128, SB / 128), blk, 0, stream>>>(
        in_bf, W1b, x_bf, b1, SB, HID, FEAT, HID, HID);

    // ---- G2: xg_r = x @ Wr_eff^T + bih_r -> bf16 [8192,4096] (perm cols) ----
    gemm_bt<true, true, false><<<dim3(GATE4 / 128, SB / 128), blk, 0, stream>>>(
        x_bf, Wrb, xg_r, bihr_p, SB, GATE4, HID, GATE4, GATE4);

    // ---- rolling LSTM: step 0 is pure cell (h=0), then 15 fused steps ----
    lstm_cell0_k<<<dim3(BATCH * HID / 256), blk, 0, stream>>>(xg_r, bhhr_p, c_buf, h_bf);
    for (int s = 1; s < SEQ; ++s) {
        lstm_step_fused<true><<<dim3(GATE4 / 64, BATCH / 64), blk, 0, stream>>>(
            h_bf, Whhrb, xg_r + (size_t)s * BATCH * GATE4, bhhr_p, c_buf, h_bf);
    }

    // ---- xg_u[15] = x[15] @ Wu_eff^T + (bih_u + bhh_u) -> bf16 (perm cols) ----
    gemm_bt<true, true, false><<<dim3(GATE4 / 128, BATCH / 128), blk, 0, stream>>>(
        x_bf + (size_t)(SEQ - 1) * BATCH * HID, Wub, xg_u, bu_p,
        BATCH, GATE4, HID, GATE4, GATE4);

    // ---- 2 unroll steps (bias folded into xg_u) ----
    for (int s = 0; s < 2; ++s) {
        lstm_step_fused<false><<<dim3(GATE4 / 64, BATCH / 64), blk, 0, stream>>>(
            h_bf, Whhub, xg_u, nullptr, c_buf, h_bf);
    }

    // ---- classifier: y = h @ Wc^T + bc -> fp32 [512,2513] ----
    gemm_bt<false, true, true><<<dim3(ACTP / 128, BATCH / 128), blk, 0, stream>>>(
        h_bf, Wcb, out, bc_p, BATCH, ACTP, HID, ACTN, ACTN);
}